// Round 15
// baseline (121.860 us; speedup 1.0000x reference)
//
#include <hip/hip_runtime.h>
#include <hip/hip_bf16.h>
#include <math.h>

// Problem constants
#define NSUB   3
#define CFEAT  1024
#define KDIM   3072          // 3 * 32 * 32
#define MDIM   1568          // 32 * 49
#define BATCH  32
#define NKL    24            // k-steps of 64 per K-half (K=1536 each)

// Output layout (flat f32): ranking[32,3] | cam 3x2x[32,7,7] | feats 3x[32,1024,7,7]
#define OUT_CAM   96
#define OUT_FEAT  9504
#define FEAT_PER_BRANCH (BATCH * CFEAT * 49)   // 1605632

// Workspace byte offsets.
#define WS_A      0
#define WS_W      (9600 * 1024)
#define WS_POOLED (WS_W + 18432 * 1024)
#define WS_H      (WS_POOLED + NSUB * BATCH * CFEAT * 4)
#define WS_CAMP   (WS_H + NSUB * BATCH * 512 * 4)

typedef __attribute__((ext_vector_type(8))) short bf16x8;
typedef __attribute__((ext_vector_type(4))) float f32x4;

__device__ __forceinline__ short b16(float f){
    __hip_bfloat16 h = __float2bfloat16(f);
    return *reinterpret_cast<short*>(&h);
}
__device__ __forceinline__ bf16x8 pack8(float4 a, float4 b){
    bf16x8 r;
    r[0]=b16(a.x); r[1]=b16(a.y); r[2]=b16(a.z); r[3]=b16(a.w);
    r[4]=b16(b.x); r[5]=b16(b.y); r[6]=b16(b.z); r[7]=b16(b.w);
    return r;
}

// global -> LDS direct copy, 16B per lane (dest = wave-uniform base + lane*16)
typedef const __attribute__((address_space(1))) void* gas1_t;
typedef __attribute__((address_space(3))) void* las3_t;
__device__ __forceinline__ void gl_lds16(const short* g, char* l){
    __builtin_amdgcn_global_load_lds((gas1_t)g, (las3_t)l, 16, 0, 0);
}

// ---------------------------------------------------------------------------
// Prep into MFMA-fragment layout (unchanged; validated rounds 7-14).
// Fragment (16x16x32 bf16 A/B operand): lane l holds row (l&15), k=(l>>4)*8+j.
// Chunk index: A: (MT64*96 + KT)*4 + mi ; W: (NTg*96 + KT)*4 + ni.
// ---------------------------------------------------------------------------
__global__ __launch_bounds__(256) void prep_frag(
    const float* __restrict__ x, const float* __restrict__ w,
    bf16x8* __restrict__ Af, bf16x8* __restrict__ Wf)
{
    int bid = blockIdx.x, t = threadIdx.x;
    if (bid < 4608) {
        int g = bid * 256 + t;
        int chunk = g >> 6, l = g & 63;
        int ni = chunk & 3, KT = (chunk >> 2) % 96, NTg = chunk / 384;
        int n = NTg * 64 + ni * 16 + (l & 15);       // 0..3071 = flat (i,c)
        int k = KT * 32 + (l >> 4) * 8;
        const float* src = w + (size_t)n * KDIM + k;
        Wf[(size_t)chunk * 64 + l] = pack8(*(const float4*)src, *(const float4*)(src + 4));
    } else {
        int g = (bid - 4608) * 256 + t;
        int chunk = g >> 6, l = g & 63;
        int mi = chunk & 3, KT = (chunk >> 2) % 96, MT = chunk / 384;
        int m  = MT * 64 + mi * 16 + (l & 15);
        int k0 = KT * 32 + (l >> 4) * 8;
        bf16x8 v;
        if (m < MDIM) {
            int b = m / 49, p = m % 49, ph = p / 7, pw = p % 7;
            int ch = k0 >> 10, r = (k0 >> 5) & 31, s = k0 & 31;
            const float* src = x + (((size_t)(b*3 + ch)*224 + ph*32 + r)*224 + pw*32 + s);
            v = pack8(*(const float4*)src, *(const float4*)(src + 4));
        } else {
            v = (bf16x8){0,0,0,0,0,0,0,0};           // pad rows: zero
        }
        Af[(size_t)chunk * 64 + l] = v;
    }
}

// ---------------------------------------------------------------------------
// Conv GEMM bf16 MFMA — INTRA-BLOCK SPLIT-K=2. R3 grid (624 blocks, 128x64
// tile) but 512 threads: waves 0-3 do K[0,1536), waves 4-7 do K[1536,3072)
// for the SAME tile; LDS reduction at the end. 4992 waves = 19.5/CU (~4/SIMD)
// — the one invariant every 50us variant lacked (R3..R14 all had 1-1.5/SIMD;
// R14 proved issue-order pipelining is NOT the fix -> TLP must be).
// A via gl_lds frag chunks (dbuf 16KB x2 per half = 64KB total); B->regs.
// No atomics, no extra workspace, deterministic.
// ---------------------------------------------------------------------------
__global__ __launch_bounds__(512, 4) void conv_mfma(
    const bf16x8* __restrict__ Af, const bf16x8* __restrict__ Wf,
    const float* __restrict__ bb, float* __restrict__ out)
{
    __shared__ __align__(16) char lds[65536];   // [half][buf][16 chunks x 1KB]

    int bid = (int)blockIdx.x;
    bid = (bid & 7) * 78 + (bid >> 3);          // bijective XCD swizzle (624=8*78)
    const int i   = bid / 208;
    const int rem = bid % 208;
    const int nt  = rem / 13, mt = rem % 13;    // mt fastest: B panel L2-hot

    const int t = threadIdx.x, wv = t >> 6, l = t & 63;
    const int h   = wv >> 2;                    // K half
    const int ws2 = wv & 3;                     // wave within half
    const int wr  = ws2 >> 1, wc = ws2 & 1;
    const int lrow = l & 15, lsl = l >> 4;
    const int hbase = h * 32768;

    // ---- A staging: wave stages slots ws2*4+q of its half; slot = m64*8+kk*4+mi
    //      chunk = (2mt+m64)*384 + h*192 + (ktl*2+kk)*4 + mi ----
    const short* Ag[4]; int Ad[4];
#pragma unroll
    for (int q = 0; q < 4; ++q) {
        int sl  = ws2*4 + q;
        int m64 = sl >> 3, kk = (sl >> 2) & 1, mi = sl & 3;
        Ag[q] = (const short*)(Af + (size_t)((2*mt + m64)*384 + h*192 + kk*4 + mi) * 64 + l);
        Ad[q] = hbase + sl * 1024;
    }

    // ---- B frag ptrs: chunk = NTg*384 + h*192 + (ktl*2+kk)*4 + (wc*2+ni) ----
    const int NTg = i*16 + nt;
    const bf16x8* Bp[2][2];
#pragma unroll
    for (int ni = 0; ni < 2; ++ni)
#pragma unroll
        for (int kk = 0; kk < 2; ++kk)
            Bp[ni][kk] = Wf + (size_t)(NTg*384 + h*192 + kk*4 + wc*2 + ni) * 64 + l;

    f32x4 acc[4][2] = {};
    bf16x8 bgA[2][2], bgB[2][2];

    // prologue: stage ktl=0 -> buf0, B(0) -> bgA
#pragma unroll
    for (int q = 0; q < 4; ++q) gl_lds16(Ag[q], lds + Ad[q]);
#pragma unroll
    for (int ni = 0; ni < 2; ++ni)
#pragma unroll
        for (int kk = 0; kk < 2; ++kk)
            bgA[ni][kk] = *Bp[ni][kk];

    auto COMPUTE = [&](int bufsel, bf16x8 (&BG)[2][2]) {
        const char* base = lds + hbase + bufsel * 16384;
        bf16x8 af[4][2];
#pragma unroll
        for (int kk = 0; kk < 2; ++kk)
#pragma unroll
            for (int mi = 0; mi < 4; ++mi)
                af[mi][kk] = *(const bf16x8*)(base + (wr*8 + kk*4 + mi)*1024 + l*16);
        __builtin_amdgcn_s_setprio(1);
#pragma unroll
        for (int kk = 0; kk < 2; ++kk)
#pragma unroll
            for (int mi = 0; mi < 4; ++mi)
#pragma unroll
                for (int ni = 0; ni < 2; ++ni)
                    acc[mi][ni] = __builtin_amdgcn_mfma_f32_16x16x32_bf16(
                        af[mi][kk], BG[ni][kk], acc[mi][ni], 0, 0, 0);
        __builtin_amdgcn_s_setprio(0);
    };

    for (int ktl = 0; ktl < NKL; ktl += 2) {
        __syncthreads();
        if (ktl + 1 < NKL) {                    // prefetch ktl+1 -> buf1
#pragma unroll
            for (int q = 0; q < 4; ++q)
                gl_lds16(Ag[q] + (size_t)(ktl+1)*512*8, lds + 16384 + Ad[q]);
#pragma unroll
            for (int ni = 0; ni < 2; ++ni)
#pragma unroll
                for (int kk = 0; kk < 2; ++kk)
                    bgB[ni][kk] = Bp[ni][kk][(size_t)(ktl+1)*512];
        }
        COMPUTE(0, bgA);
        __syncthreads();
        if (ktl + 2 < NKL) {                    // prefetch ktl+2 -> buf0
#pragma unroll
            for (int q = 0; q < 4; ++q)
                gl_lds16(Ag[q] + (size_t)(ktl+2)*512*8, lds + Ad[q]);
#pragma unroll
            for (int ni = 0; ni < 2; ++ni)
#pragma unroll
                for (int kk = 0; kk < 2; ++kk)
                    bgA[ni][kk] = Bp[ni][kk][(size_t)(ktl+2)*512];
        }
        COMPUTE(1, bgB);
    }

    // ---- split-K reduction: h1 -> LDS (pad-33 rows, conflict-free), h0 adds ----
    __syncthreads();
    float* red = (float*)lds;                   // reuse; pair region = 2112 floats
    if (h == 1) {
#pragma unroll
        for (int mi = 0; mi < 4; ++mi)
#pragma unroll
            for (int ni = 0; ni < 2; ++ni)
#pragma unroll
                for (int r = 0; r < 4; ++r)
                    red[ws2*2112 + (mi*16 + lsl*4 + r)*33 + ni*16 + lrow] = acc[mi][ni][r];
    }
    __syncthreads();
    if (h == 0) {
        float bias[2];
#pragma unroll
        for (int ni = 0; ni < 2; ++ni)
            bias[ni] = bb[i*CFEAT + nt*64 + wc*32 + ni*16 + lrow];
        float* featb = out + OUT_FEAT + (size_t)i * FEAT_PER_BRANCH;
#pragma unroll
        for (int mi = 0; mi < 4; ++mi) {
            int mbase = mt*128 + wr*64 + mi*16 + lsl*4;
#pragma unroll
            for (int r = 0; r < 4; ++r) {
                int m = mbase + r;
                if (m >= MDIM) continue;
                int b = m/49, p = m%49;
#pragma unroll
                for (int ni = 0; ni < 2; ++ni) {
                    int n = nt*64 + wc*32 + ni*16 + lrow;
                    float v = acc[mi][ni][r]
                            + red[ws2*2112 + (mi*16 + lsl*4 + r)*33 + ni*16 + lrow]
                            + bias[ni];
                    featb[(size_t)(b*CFEAT + n)*49 + p] = v;
                }
            }
        }
    }
}

// ---------------------------------------------------------------------------
// Pool + partial CAM: 768 blocks (i, b, 128-channel chunk), 128 threads.
// ---------------------------------------------------------------------------
__global__ __launch_bounds__(128) void cam_pool(
    const float* __restrict__ feat, const float* __restrict__ cls_w,
    float* __restrict__ pooled, float* __restrict__ camp)
{
    __shared__ float fs[128][50];
    int bid = blockIdx.x;                  // (i*32+b)*8 + ch
    int i = bid >> 8, b = (bid >> 3) & 31, ch = bid & 7;
    int t = threadIdx.x;
    int c0 = ch * 128;
    const float* f = feat + ((size_t)(i*BATCH + b) * CFEAT + c0) * 49;

    for (int qq = 0; qq < 49; ++qq) {
        int e = qq*128 + t;
        fs[e / 49][e % 49] = f[e];
    }
    __syncthreads();

    {
        float s = 0.f;
#pragma unroll
        for (int k = 0; k < 49; ++k) s += fs[t][k];
        pooled[(size_t)(i*BATCH + b) * CFEAT + c0 + t] = s * (1.f/49.f);
    }

    if (t < 98) {
        int o = t / 49, p = t % 49;
        const float* w = cls_w + (size_t)i * 2 * CFEAT + o * CFEAT + c0;
        float s = 0.f;
        for (int c = 0; c < 128; ++c) s += w[c] * fs[c][p];
        camp[(size_t)bid * 98 + t] = s;
    }
}

// ---------------------------------------------------------------------------
// MLP layer 1 (blocks 0..47) + CAM finalize (blocks 48..84).
// ---------------------------------------------------------------------------
__global__ __launch_bounds__(256) void mlp1_kernel(
    const float* __restrict__ pooled, const float* __restrict__ p1w,
    const float* __restrict__ p1b, float* __restrict__ h,
    const float* __restrict__ camp, float* __restrict__ out_cam)
{
    if (blockIdx.x >= 48) {                 // CAM finalize: sum 8 chunk partials
        int fid = (blockIdx.x - 48) * 256 + threadIdx.x;
        if (fid < NSUB * 2 * MDIM) {
            int io = fid / MDIM, rem = fid % MDIM;
            int b = rem / 49, p = rem % 49;
            int i = io >> 1, o = io & 1;
            float s = 0.f;
#pragma unroll
            for (int c = 0; c < 8; ++c)
                s += camp[(size_t)(((i*BATCH + b)*8) + c) * 98 + o*49 + p];
            out_cam[fid] = fmaxf(s, 0.f);
        }
        return;
    }
    __shared__ float ps[32 * 256];
    int i = blockIdx.x >> 4, jc = blockIdx.x & 15;
    int t = threadIdx.x;
    int j = jc*32 + (t & 31);
    int bg = (t >> 5) * 4;
    float acc[4] = {};
    const float* wrow = p1w + ((size_t)i*512 + j) * CFEAT;
    for (int kc = 0; kc < 4; ++kc) {
        __syncthreads();
#pragma unroll
        for (int qq = 0; qq < 8; ++qq) {
            int f4 = t + qq*256;                 // 0..2047 float4s
            int b = f4 >> 6, k4 = (f4 & 63) * 4;
            *(float4*)&ps[b*256 + k4] =
                *(const float4*)&pooled[((size_t)i*32 + b)*CFEAT + kc*256 + k4];
        }
        __syncthreads();
        const float* wk = wrow + kc*256;
        for (int k = 0; k < 256; k += 4) {
            float4 w4 = *(const float4*)(wk + k);
#pragma unroll
            for (int qq = 0; qq < 4; ++qq) {
                const float* pr = &ps[(bg + qq)*256 + k];  // wave-uniform: broadcast
                acc[qq] += w4.x*pr[0] + w4.y*pr[1] + w4.z*pr[2] + w4.w*pr[3];
            }
        }
    }
    float bias = p1b[i*512 + j];
#pragma unroll
    for (int qq = 0; qq < 4; ++qq)
        h[((size_t)i*32 + bg + qq)*512 + j] = fmaxf(acc[qq] + bias, 0.f);
}

// ---------------------------------------------------------------------------
// MLP layer 2 + softmax[:,1]: block per branch.
// ---------------------------------------------------------------------------
__global__ void mlp2_kernel(const float* __restrict__ h, const float* __restrict__ p2w,
                            const float* __restrict__ p2b, float* __restrict__ out)
{
    __shared__ float part[256];
    int i = blockIdx.x, t = threadIdx.x;
    int b = t & 31, kc = t >> 5;                 // kc 0..7, 64 k each
    const float* hv = h + ((size_t)i*32 + b)*512 + kc*64;
    const float* w0 = p2w + (size_t)i*1024 + kc*64;
    const float* w1 = w0 + 512;
    float s = 0.f;
    for (int k = 0; k < 64; ++k) s += hv[k] * (w1[k] - w0[k]);
    part[t] = s;
    __syncthreads();
    if (t < 32) {
        float d = 0.f;
#pragma unroll
        for (int qq = 0; qq < 8; ++qq) d += part[qq*32 + t];
        d += p2b[i*2 + 1] - p2b[i*2 + 0];
        out[b*NSUB + i] = 1.f / (1.f + expf(-d));
    }
}

// ---------------------------------------------------------------------------
extern "C" void kernel_launch(void* const* d_in, const int* in_sizes, int n_in,
                              void* d_out, int out_size, void* d_ws, size_t ws_size,
                              hipStream_t stream)
{
    const float* x    = (const float*)d_in[0];
    const float* Wb   = (const float*)d_in[1];
    const float* bbp  = (const float*)d_in[2];
    const float* p1w  = (const float*)d_in[3];
    const float* p1b  = (const float*)d_in[4];
    const float* p2w  = (const float*)d_in[5];
    const float* p2b  = (const float*)d_in[6];
    const float* clsw = (const float*)d_in[7];
    float* out = (float*)d_out;

    char* ws = (char*)d_ws;
    bf16x8* Af    = (bf16x8*)(ws + WS_A);
    bf16x8* Wf    = (bf16x8*)(ws + WS_W);
    float* pooled = (float*)(ws + WS_POOLED);
    float* hbuf   = (float*)(ws + WS_H);
    float* camp   = (float*)(ws + WS_CAMP);

    prep_frag<<<4608 + 2400, 256, 0, stream>>>(x, Wb, Af, Wf);
    conv_mfma<<<624, 512, 0, stream>>>(Af, Wf, bbp, out);
    cam_pool<<<NSUB*BATCH*8, 128, 0, stream>>>(out + OUT_FEAT, clsw, pooled, camp);
    mlp1_kernel<<<48 + 37, 256, 0, stream>>>(pooled, p1w, p1b, hbuf, camp, out + OUT_CAM);
    mlp2_kernel<<<NSUB, 256, 0, stream>>>(hbuf, p2w, p2b, out);
}

// Round 16
// 109.938 us; speedup vs baseline: 1.1084x; 1.1084x over previous
//
#include <hip/hip_runtime.h>
#include <hip/hip_bf16.h>
#include <math.h>

// Problem constants
#define NSUB   3
#define CFEAT  1024
#define KDIM   3072          // 3 * 32 * 32
#define MDIM   1568          // 32 * 49
#define BATCH  32
#define NKT    96            // K tiles of 32

// Output layout (flat f32): ranking[32,3] | cam 3x2x[32,7,7] | feats 3x[32,1024,7,7]
#define OUT_CAM   96
#define OUT_FEAT  9504
#define FEAT_PER_BRANCH (BATCH * CFEAT * 49)   // 1605632

// Workspace byte offsets.
#define WS_A      0
#define WS_W      (9600 * 1024)
#define WS_POOLED (WS_W + 18432 * 1024)
#define WS_H      (WS_POOLED + NSUB * BATCH * CFEAT * 4)
#define WS_CAMP   (WS_H + NSUB * BATCH * 512 * 4)

typedef __attribute__((ext_vector_type(8))) short bf16x8;
typedef __attribute__((ext_vector_type(4))) float f32x4;

__device__ __forceinline__ short b16(float f){
    __hip_bfloat16 h = __float2bfloat16(f);
    return *reinterpret_cast<short*>(&h);
}
__device__ __forceinline__ bf16x8 pack8(float4 a, float4 b){
    bf16x8 r;
    r[0]=b16(a.x); r[1]=b16(a.y); r[2]=b16(a.z); r[3]=b16(a.w);
    r[4]=b16(b.x); r[5]=b16(b.y); r[6]=b16(b.z); r[7]=b16(b.w);
    return r;
}

// ---------------------------------------------------------------------------
// Prep into MFMA-fragment layout (unchanged; validated rounds 7-15).
// Fragment (16x16x32 bf16 A/B operand): lane l holds row (l&15), k=(l>>4)*8+j.
// Chunk index: A: (MT64*96 + KT)*4 + mi ; W: (NTg*96 + KT)*4 + ni.
// ---------------------------------------------------------------------------
__global__ __launch_bounds__(256) void prep_frag(
    const float* __restrict__ x, const float* __restrict__ w,
    bf16x8* __restrict__ Af, bf16x8* __restrict__ Wf)
{
    int bid = blockIdx.x, t = threadIdx.x;
    if (bid < 4608) {
        int g = bid * 256 + t;
        int chunk = g >> 6, l = g & 63;
        int ni = chunk & 3, KT = (chunk >> 2) % 96, NTg = chunk / 384;
        int n = NTg * 64 + ni * 16 + (l & 15);       // 0..3071 = flat (i,c)
        int k = KT * 32 + (l >> 4) * 8;
        const float* src = w + (size_t)n * KDIM + k;
        Wf[(size_t)chunk * 64 + l] = pack8(*(const float4*)src, *(const float4*)(src + 4));
    } else {
        int g = (bid - 4608) * 256 + t;
        int chunk = g >> 6, l = g & 63;
        int mi = chunk & 3, KT = (chunk >> 2) % 96, MT = chunk / 384;
        int m  = MT * 64 + mi * 16 + (l & 15);
        int k0 = KT * 32 + (l >> 4) * 8;
        bf16x8 v;
        if (m < MDIM) {
            int b = m / 49, p = m % 49, ph = p / 7, pw = p % 7;
            int ch = k0 >> 10, r = (k0 >> 5) & 31, s = k0 & 31;
            const float* src = x + (((size_t)(b*3 + ch)*224 + ph*32 + r)*224 + pw*32 + s);
            v = pack8(*(const float4*)src, *(const float4*)(src + 4));
        } else {
            v = (bf16x8){0,0,0,0,0,0,0,0};           // pad rows: zero
        }
        Af[(size_t)chunk * 64 + l] = v;
    }
}

// ---------------------------------------------------------------------------
// Conv GEMM bf16 MFMA — round-9 body VERBATIM (measured best: 50.0 us; plain
// loads, depth-4 named buffers + sched_barrier, no barriers/staging LDS,
// LDS epilogue). ONLY CHANGE: within-XCD block order inverted to MT-OUTER /
// column-INNER. R14 evidence: FETCH=100MB vs 29MB unique -> A (9.6MB) was
// L2-thrashing because MT-fastest order made the ~32 concurrent blocks of an
// XCD span all 25 A-tiles. New map: each XCD owns 3 fixed column-pair groups
// (B 2.4MB L2-resident all kernel); A tiles consumed 3-blocks-back-to-back
// (streaming reuse, concurrent set ~6.6MB). Expected A inflow 230->77MB.
//   d&7 = XCD (HW round-robin); c = d>>3 in [0,75); MT = c/3;
//   g = xcd*3 + c%3 in [0,24); i = g>>3; NTb = g&7.
// ---------------------------------------------------------------------------
__global__ __launch_bounds__(128, 2) void conv_mfma(
    const bf16x8* __restrict__ Af, const bf16x8* __restrict__ Wf,
    const float* __restrict__ bb, float* __restrict__ out)
{
    __shared__ float eplds[2][64 * 65];         // epilogue only

    const int d   = (int)blockIdx.x;            // 0..599
    const int xcd = d & 7;
    const int c   = d >> 3;                     // 0..74
    const int MT  = c / 3;                      // A tile: 3 consecutive blocks
    const int g   = xcd * 3 + (c % 3);          // column-pair group 0..23
    const int i   = g >> 3;
    const int NTb = g & 7;

    const int wv = threadIdx.x >> 6, l = threadIdx.x & 63;
    const int NT = NTb + wv * 8;
    const int lrow = l & 15, q = l >> 4;

    const bf16x8* Ab = Af + (size_t)(MT * 384) * 64 + l;          // + KT*256 + mi*64
    const bf16x8* Bb = Wf + (size_t)((i*16 + NT) * 384) * 64 + l; // + KT*256 + ni*64

    f32x4 acc[4][4] = {};
    bf16x8 a0[4], b0[4], a1[4], b1[4], a2[4], b2[4], a3[4], b3[4];

    auto LOADT = [&](bf16x8 (&Ad)[4], bf16x8 (&Bd)[4], int KT){
        const bf16x8* An = Ab + KT * 256;
        const bf16x8* Bn = Bb + KT * 256;
#pragma unroll
        for (int m2 = 0; m2 < 4; ++m2) { Ad[m2] = An[m2*64]; Bd[m2] = Bn[m2*64]; }
    };
    auto MFMAT = [&](bf16x8 (&As)[4], bf16x8 (&Bs)[4]){
        __builtin_amdgcn_s_setprio(1);
#pragma unroll
        for (int mi = 0; mi < 4; ++mi)
#pragma unroll
            for (int ni = 0; ni < 4; ++ni)
                acc[mi][ni] = __builtin_amdgcn_mfma_f32_16x16x32_bf16(
                    As[mi], Bs[ni], acc[mi][ni], 0, 0, 0);
        __builtin_amdgcn_s_setprio(0);
    };
#define SB() __builtin_amdgcn_sched_barrier(0)

    // prologue: fill depth-4 (32 loads in flight)
    LOADT(a0, b0, 0); LOADT(a1, b1, 1); LOADT(a2, b2, 2); LOADT(a3, b3, 3);
    SB();
    for (int kt = 0; kt < NKT; kt += 4) {
        MFMAT(a0, b0); SB();
        if (kt + 4 < NKT) { LOADT(a0, b0, kt + 4); } SB();
        MFMAT(a1, b1); SB();
        if (kt + 5 < NKT) { LOADT(a1, b1, kt + 5); } SB();
        MFMAT(a2, b2); SB();
        if (kt + 6 < NKT) { LOADT(a2, b2, kt + 6); } SB();
        MFMAT(a3, b3); SB();
        if (kt + 7 < NKT) { LOADT(a3, b3, kt + 7); } SB();
    }
#undef SB

    // ---- epilogue: acc -> per-wave LDS tile -> coalesced global writes ----
    float bias[4];
#pragma unroll
    for (int ni = 0; ni < 4; ++ni)
        bias[ni] = bb[i*CFEAT + NT*64 + ni*16 + lrow];
    float* ep = eplds[wv];
#pragma unroll
    for (int mi = 0; mi < 4; ++mi)
#pragma unroll
        for (int ni = 0; ni < 4; ++ni)
#pragma unroll
            for (int rr = 0; rr < 4; ++rr)
                ep[(mi*16 + q*4 + rr) * 65 + ni*16 + lrow] = acc[mi][ni][rr] + bias[ni];

    // same-wave LDS readback: compiler orders via lgkmcnt
    float* featb = out + OUT_FEAT + (size_t)i * FEAT_PER_BRANCH;
    int m = MT*64 + l;
    if (m < MDIM) {
        int b = m / 49, p = m % 49;
        float* base = featb + (size_t)(b*CFEAT + NT*64) * 49 + p;
#pragma unroll 8
        for (int cc = 0; cc < 64; ++cc)
            base[cc * 49] = ep[l*65 + cc];
    }
}

// ---------------------------------------------------------------------------
// Pool + partial CAM: 768 blocks (i, b, 128-channel chunk), 128 threads.
// ---------------------------------------------------------------------------
__global__ __launch_bounds__(128) void cam_pool(
    const float* __restrict__ feat, const float* __restrict__ cls_w,
    float* __restrict__ pooled, float* __restrict__ camp)
{
    __shared__ float fs[128][50];
    int bid = blockIdx.x;                  // (i*32+b)*8 + ch
    int i = bid >> 8, b = (bid >> 3) & 31, ch = bid & 7;
    int t = threadIdx.x;
    int c0 = ch * 128;
    const float* f = feat + ((size_t)(i*BATCH + b) * CFEAT + c0) * 49;

    for (int qq = 0; qq < 49; ++qq) {
        int e = qq*128 + t;
        fs[e / 49][e % 49] = f[e];
    }
    __syncthreads();

    {
        float s = 0.f;
#pragma unroll
        for (int k = 0; k < 49; ++k) s += fs[t][k];
        pooled[(size_t)(i*BATCH + b) * CFEAT + c0 + t] = s * (1.f/49.f);
    }

    if (t < 98) {
        int o = t / 49, p = t % 49;
        const float* w = cls_w + (size_t)i * 2 * CFEAT + o * CFEAT + c0;
        float s = 0.f;
        for (int c = 0; c < 128; ++c) s += w[c] * fs[c][p];
        camp[(size_t)bid * 98 + t] = s;
    }
}

// ---------------------------------------------------------------------------
// MLP layer 1 (blocks 0..47) + CAM finalize (blocks 48..84).
// ---------------------------------------------------------------------------
__global__ __launch_bounds__(256) void mlp1_kernel(
    const float* __restrict__ pooled, const float* __restrict__ p1w,
    const float* __restrict__ p1b, float* __restrict__ h,
    const float* __restrict__ camp, float* __restrict__ out_cam)
{
    if (blockIdx.x >= 48) {                 // CAM finalize: sum 8 chunk partials
        int fid = (blockIdx.x - 48) * 256 + threadIdx.x;
        if (fid < NSUB * 2 * MDIM) {
            int io = fid / MDIM, rem = fid % MDIM;
            int b = rem / 49, p = rem % 49;
            int i = io >> 1, o = io & 1;
            float s = 0.f;
#pragma unroll
            for (int c = 0; c < 8; ++c)
                s += camp[(size_t)(((i*BATCH + b)*8) + c) * 98 + o*49 + p];
            out_cam[fid] = fmaxf(s, 0.f);
        }
        return;
    }
    __shared__ float ps[32 * 256];
    int i = blockIdx.x >> 4, jc = blockIdx.x & 15;
    int t = threadIdx.x;
    int j = jc*32 + (t & 31);
    int bg = (t >> 5) * 4;
    float acc[4] = {};
    const float* wrow = p1w + ((size_t)i*512 + j) * CFEAT;
    for (int kc = 0; kc < 4; ++kc) {
        __syncthreads();
#pragma unroll
        for (int qq = 0; qq < 8; ++qq) {
            int f4 = t + qq*256;                 // 0..2047 float4s
            int b = f4 >> 6, k4 = (f4 & 63) * 4;
            *(float4*)&ps[b*256 + k4] =
                *(const float4*)&pooled[((size_t)i*32 + b)*CFEAT + kc*256 + k4];
        }
        __syncthreads();
        const float* wk = wrow + kc*256;
        for (int k = 0; k < 256; k += 4) {
            float4 w4 = *(const float4*)(wk + k);
#pragma unroll
            for (int qq = 0; qq < 4; ++qq) {
                const float* pr = &ps[(bg + qq)*256 + k];  // wave-uniform: broadcast
                acc[qq] += w4.x*pr[0] + w4.y*pr[1] + w4.z*pr[2] + w4.w*pr[3];
            }
        }
    }
    float bias = p1b[i*512 + j];
#pragma unroll
    for (int qq = 0; qq < 4; ++qq)
        h[((size_t)i*32 + bg + qq)*512 + j] = fmaxf(acc[qq] + bias, 0.f);
}

// ---------------------------------------------------------------------------
// MLP layer 2 + softmax[:,1]: block per branch.
// ---------------------------------------------------------------------------
__global__ void mlp2_kernel(const float* __restrict__ h, const float* __restrict__ p2w,
                            const float* __restrict__ p2b, float* __restrict__ out)
{
    __shared__ float part[256];
    int i = blockIdx.x, t = threadIdx.x;
    int b = t & 31, kc = t >> 5;                 // kc 0..7, 64 k each
    const float* hv = h + ((size_t)i*32 + b)*512 + kc*64;
    const float* w0 = p2w + (size_t)i*1024 + kc*64;
    const float* w1 = w0 + 512;
    float s = 0.f;
    for (int k = 0; k < 64; ++k) s += hv[k] * (w1[k] - w0[k]);
    part[t] = s;
    __syncthreads();
    if (t < 32) {
        float d = 0.f;
#pragma unroll
        for (int qq = 0; qq < 8; ++qq) d += part[qq*32 + t];
        d += p2b[i*2 + 1] - p2b[i*2 + 0];
        out[b*NSUB + i] = 1.f / (1.f + expf(-d));
    }
}

// ---------------------------------------------------------------------------
extern "C" void kernel_launch(void* const* d_in, const int* in_sizes, int n_in,
                              void* d_out, int out_size, void* d_ws, size_t ws_size,
                              hipStream_t stream)
{
    const float* x    = (const float*)d_in[0];
    const float* Wb   = (const float*)d_in[1];
    const float* bbp  = (const float*)d_in[2];
    const float* p1w  = (const float*)d_in[3];
    const float* p1b  = (const float*)d_in[4];
    const float* p2w  = (const float*)d_in[5];
    const float* p2b  = (const float*)d_in[6];
    const float* clsw = (const float*)d_in[7];
    float* out = (float*)d_out;

    char* ws = (char*)d_ws;
    bf16x8* Af    = (bf16x8*)(ws + WS_A);
    bf16x8* Wf    = (bf16x8*)(ws + WS_W);
    float* pooled = (float*)(ws + WS_POOLED);
    float* hbuf   = (float*)(ws + WS_H);
    float* camp   = (float*)(ws + WS_CAMP);

    prep_frag<<<4608 + 2400, 256, 0, stream>>>(x, Wb, Af, Wf);
    conv_mfma<<<600, 128, 0, stream>>>(Af, Wf, bbp, out);
    cam_pool<<<NSUB*BATCH*8, 128, 0, stream>>>(out + OUT_FEAT, clsw, pooled, camp);
    mlp1_kernel<<<48 + 37, 256, 0, stream>>>(pooled, p1w, p1b, hbuf, camp, out + OUT_CAM);
    mlp2_kernel<<<NSUB, 256, 0, stream>>>(hbuf, p2w, p2b, out);
}